// Round 1
// baseline (462.068 us; speedup 1.0000x reference)
//
#include <hip/hip_runtime.h>
#include <hip/hip_bf16.h>

#define B_ 4
#define L_ 4096
#define D_ 1024
#define N_ 32
#define MTOT (B_*L_)   // 16384
#define TCH 128        // scan chunk length
#define WARM 32        // scan warm-up steps (|A|^32 < 1e-20)

typedef __bf16 bf16;
typedef __attribute__((ext_vector_type(8))) __bf16 bf16x8;
typedef __attribute__((ext_vector_type(4))) __bf16 bf16x4;
typedef __attribute__((ext_vector_type(4))) float f32x4;

__device__ __forceinline__ void gload_lds16(const void* gsrc, void* ldst) {
  // global -> LDS direct, 16B per lane. LDS dest is wave-uniform base + lane*16.
  __builtin_amdgcn_global_load_lds(
      (__attribute__((address_space(1))) void*)(unsigned long long)gsrc,
      (__attribute__((address_space(3))) void*)ldst, 16, 0, 0);
}

// ---------------- convert x -> bf16 ----------------
__global__ __launch_bounds__(256) void cvt_x_kernel(const float* __restrict__ x,
                                                    bf16* __restrict__ xb) {
  size_t i = ((size_t)blockIdx.x * 256 + threadIdx.x) * 4;
  float4 v = *(const float4*)(x + i);
  bf16x4 o = {(bf16)v.x, (bf16)v.y, (bf16)v.z, (bf16)v.w};
  *(bf16x4*)(xb + i) = o;
}

// ---------------- convert weights, build A = -exp(clip(A_log)) ----------------
__global__ __launch_bounds__(256) void cvt_w_kernel(
    const float* __restrict__ in_w, const float* __restrict__ out_w,
    const float* __restrict__ B_w, const float* __restrict__ C_w,
    const float* __restrict__ A_log, const float* __restrict__ B_b,
    const float* __restrict__ C_b,
    bf16* __restrict__ in_wb, bf16* __restrict__ out_wb, bf16* __restrict__ bcw,
    float* __restrict__ Aexp, float* __restrict__ bias_bc) {
  const int stride = gridDim.x * 256;
  const int i0 = blockIdx.x * 256 + threadIdx.x;
  for (int j = i0; j < 2 * D_ * D_; j += stride) in_wb[j] = (bf16)in_w[j];
  for (int j = i0; j < D_ * D_; j += stride) out_wb[j] = (bf16)out_w[j];
  for (int j = i0; j < N_ * D_; j += stride) {
    bcw[j] = (bf16)B_w[j];
    bcw[N_ * D_ + j] = (bf16)C_w[j];
  }
  for (int j = i0; j < D_ * N_; j += stride)
    Aexp[j] = -expf(fminf(fmaxf(A_log[j], -5.f), 2.f));
  if (i0 < N_) { bias_bc[i0] = B_b[i0]; bias_bc[N_ + i0] = C_b[i0]; }
}

// ---------------- generic bf16 MFMA GEMM: C[M,Ncols] = A[M,K] @ W[Ncols,K]^T + bias (+resid) ----
template <int BM, int BN, int WAVES_M, int WAVES_N, bool OUT_BF16, bool ADD_RESID>
__global__ __launch_bounds__(256) void gemm_kernel(
    const bf16* __restrict__ Ag, const bf16* __restrict__ Wg,
    const float* __restrict__ bias, const float* __restrict__ resid,
    void* __restrict__ Cg, int Ncols, int K) {
  constexpr int BK = 32;
  constexpr int WM = BM / WAVES_M;
  constexpr int WN = BN / WAVES_N;
  constexpr int MI = WM / 16;
  constexpr int NI = WN / 16;
  __shared__ alignas(16) bf16 As[BM][BK];
  __shared__ alignas(16) bf16 Bs[BN][BK];
  const int tid = threadIdx.x;
  const int lane = tid & 63;
  const int wid = tid >> 6;
  const int wm = wid / WAVES_N;
  const int wn = wid % WAVES_N;
  const int l15 = lane & 15;
  const int lh = lane >> 4;
  const int row0 = blockIdx.x * BM;
  const int col0 = blockIdx.y * BN;

  f32x4 acc[MI][NI] = {};

  for (int k0 = 0; k0 < K; k0 += BK) {
    // stage A tile [BM][BK] (rows of 64B, linear LDS)
#pragma unroll
    for (int i = 0; i < (BM * BK * 2 / 16) / 256; ++i) {
      const int chunk = tid + i * 256;
      const int o = chunk * 16;
      const int r = o >> 6;
      const int kb = (o & 63) >> 1;
      gload_lds16(Ag + (size_t)(row0 + r) * K + (k0 + kb),
                  (bf16*)&As[0][0] + (size_t)(wid * 64 + i * 256) * 8);
    }
    // stage W tile [BN][BK]
#pragma unroll
    for (int i = 0; i < (BN * BK * 2 / 16) / 256; ++i) {
      const int chunk = tid + i * 256;
      const int o = chunk * 16;
      const int r = o >> 6;
      const int kb = (o & 63) >> 1;
      gload_lds16(Wg + (size_t)(col0 + r) * K + (k0 + kb),
                  (bf16*)&Bs[0][0] + (size_t)(wid * 64 + i * 256) * 8);
    }
    __syncthreads();  // drains vmcnt (incl. global_load_lds) before reads

    bf16x8 af[MI], bfv[NI];
#pragma unroll
    for (int mi = 0; mi < MI; ++mi)
      af[mi] = *(const bf16x8*)&As[wm * WM + mi * 16 + l15][lh * 8];
#pragma unroll
    for (int ni = 0; ni < NI; ++ni)
      bfv[ni] = *(const bf16x8*)&Bs[wn * WN + ni * 16 + l15][lh * 8];
#pragma unroll
    for (int mi = 0; mi < MI; ++mi)
#pragma unroll
      for (int ni = 0; ni < NI; ++ni)
        acc[mi][ni] = __builtin_amdgcn_mfma_f32_16x16x32_bf16(
            af[mi], bfv[ni], acc[mi][ni], 0, 0, 0);
    __syncthreads();  // protect LDS before next-iter overwrite
  }

  // epilogue: C/D layout col=lane&15, row=(lane>>4)*4+reg
#pragma unroll
  for (int mi = 0; mi < MI; ++mi) {
#pragma unroll
    for (int ni = 0; ni < NI; ++ni) {
      const int c = col0 + wn * WN + ni * 16 + l15;
      const float bv = bias[c];
#pragma unroll
      for (int j = 0; j < 4; ++j) {
        const int r = row0 + wm * WM + mi * 16 + lh * 4 + j;
        float v = acc[mi][ni][j] + bv;
        if constexpr (ADD_RESID) v += resid[(size_t)r * Ncols + c];
        if constexpr (OUT_BF16)
          ((bf16*)Cg)[(size_t)r * Ncols + c] = (bf16)v;
        else
          ((float*)Cg)[(size_t)r * Ncols + c] = v;
      }
    }
  }
}

// ---------------- depthwise conv(k=4, pad 2) + bias + SiLU ----------------
__global__ __launch_bounds__(256) void conv_silu_kernel(
    const bf16* __restrict__ xz, const float* __restrict__ conv_w,
    const float* __restrict__ conv_b, bf16* __restrict__ xc) {
  const int idx = blockIdx.x * 256 + threadIdx.x;  // B*L*(D/8) threads
  const int d8 = idx & (D_ / 8 - 1);
  const int bt = idx >> 7;          // D_/8 == 128
  const int t = bt & (L_ - 1);
  const int b = bt >> 12;           // L_ == 4096
  const int d = d8 * 8;

  float accv[8];
  float4 w4[8];
#pragma unroll
  for (int j = 0; j < 8; ++j) {
    accv[j] = conv_b[d + j];
    w4[j] = *(const float4*)(conv_w + (size_t)(d + j) * 4);
  }
#pragma unroll
  for (int k = 0; k < 4; ++k) {
    const int tt = t + k - 2;
    if (tt < 0 || tt >= L_) continue;
    const bf16x8 xv = *(const bf16x8*)(xz + (size_t)(b * L_ + tt) * (2 * D_) + d);
#pragma unroll
    for (int j = 0; j < 8; ++j) {
      const float wk = (k == 0) ? w4[j].x : (k == 1) ? w4[j].y : (k == 2) ? w4[j].z : w4[j].w;
      accv[j] += (float)xv[j] * wk;
    }
  }
  bf16x8 o;
#pragma unroll
  for (int j = 0; j < 8; ++j) {
    const float v = accv[j];
    o[j] = (bf16)(v / (1.f + __expf(-v)));
  }
  *(bf16x8*)(xc + (size_t)(b * L_ + t) * D_ + d) = o;
}

// ---------------- chunked selective scan + SiLU(z) gating ----------------
__global__ __launch_bounds__(256) void scan_kernel(
    const bf16* __restrict__ xc, const float* __restrict__ BC,
    const bf16* __restrict__ xz, const float* __restrict__ Aexp,
    bf16* __restrict__ y) {
  const int dg = blockIdx.x, chunk = blockIdx.y, b = blockIdx.z;
  const int d = dg * 256 + threadIdx.x;
  const int t0 = chunk * TCH;
  const int tstart = (t0 >= WARM) ? (t0 - WARM) : 0;  // chunk 0: exact (s=0 at t=0)
  const int tend = t0 + TCH;

  float Ar[N_], s[N_];
#pragma unroll
  for (int n = 0; n < N_; ++n) { Ar[n] = Aexp[d * N_ + n]; s[n] = 0.f; }

  const bf16* xcp = xc + (size_t)b * L_ * D_ + d;
  const bf16* zp  = xz + (size_t)b * L_ * (2 * D_) + D_ + d;
  bf16* yp        = y + (size_t)b * L_ * D_ + d;
  const float4* bcp = (const float4*)(BC + (size_t)b * L_ * 64);

  for (int t = tstart; t < tend; ++t) {
    const float4* rp = bcp + (size_t)t * 16;  // block-uniform address -> broadcast/s_load
    const float xt = (float)xcp[(size_t)t * D_];
    float y0 = 0.f, y1 = 0.f, y2 = 0.f, y3 = 0.f;
#pragma unroll
    for (int q = 0; q < 8; ++q) {
      const float4 bv = rp[q];
      const float4 cv = rp[8 + q];
      { const int n = 4*q;   s[n] = fminf(fmaxf(fmaf(s[n], Ar[n], bv.x * xt), -10.f), 10.f); y0 = fmaf(cv.x, s[n], y0); }
      { const int n = 4*q+1; s[n] = fminf(fmaxf(fmaf(s[n], Ar[n], bv.y * xt), -10.f), 10.f); y1 = fmaf(cv.y, s[n], y1); }
      { const int n = 4*q+2; s[n] = fminf(fmaxf(fmaf(s[n], Ar[n], bv.z * xt), -10.f), 10.f); y2 = fmaf(cv.z, s[n], y2); }
      { const int n = 4*q+3; s[n] = fminf(fmaxf(fmaf(s[n], Ar[n], bv.w * xt), -10.f), 10.f); y3 = fmaf(cv.w, s[n], y3); }
    }
    if (t >= t0) {
      const float zt = (float)zp[(size_t)t * (2 * D_)];
      const float sz = zt / (1.f + __expf(-zt));
      yp[(size_t)t * D_] = (bf16)(((y0 + y1) + (y2 + y3)) * sz);
    }
  }
}

// ---------------- row LayerNorm ----------------
__global__ __launch_bounds__(256) void ln_kernel(const float* __restrict__ h,
                                                 const float* __restrict__ ln_w,
                                                 const float* __restrict__ ln_b,
                                                 float* __restrict__ out) {
  const int row = blockIdx.x;
  const int tid = threadIdx.x;
  const float4 v = ((const float4*)(h + (size_t)row * D_))[tid];
  float sum = v.x + v.y + v.z + v.w;
  float sq = v.x * v.x + v.y * v.y + v.z * v.z + v.w * v.w;
#pragma unroll
  for (int off = 32; off >= 1; off >>= 1) {
    sum += __shfl_xor(sum, off);
    sq += __shfl_xor(sq, off);
  }
  __shared__ float red[8];
  const int wid = tid >> 6;
  if ((tid & 63) == 0) { red[wid] = sum; red[4 + wid] = sq; }
  __syncthreads();
  sum = red[0] + red[1] + red[2] + red[3];
  sq = red[4] + red[5] + red[6] + red[7];
  const float mu = sum * (1.f / D_);
  const float var = sq * (1.f / D_) - mu * mu;
  const float inv = rsqrtf(var + 1e-5f);
  const float4 w4 = ((const float4*)ln_w)[tid];
  const float4 b4 = ((const float4*)ln_b)[tid];
  float4 o;
  o.x = (v.x - mu) * inv * w4.x + b4.x;
  o.y = (v.y - mu) * inv * w4.y + b4.y;
  o.z = (v.z - mu) * inv * w4.z + b4.z;
  o.w = (v.w - mu) * inv * w4.w + b4.w;
  ((float4*)(out + (size_t)row * D_))[tid] = o;
}

extern "C" void kernel_launch(void* const* d_in, const int* in_sizes, int n_in,
                              void* d_out, int out_size, void* d_ws, size_t ws_size,
                              hipStream_t stream) {
  (void)in_sizes; (void)n_in; (void)out_size; (void)ws_size;
  const float* x      = (const float*)d_in[0];
  const float* in_w   = (const float*)d_in[1];
  const float* in_b   = (const float*)d_in[2];
  const float* conv_w = (const float*)d_in[3];
  const float* conv_b = (const float*)d_in[4];
  const float* A_log  = (const float*)d_in[5];
  const float* B_w    = (const float*)d_in[6];
  const float* B_b    = (const float*)d_in[7];
  const float* C_w    = (const float*)d_in[8];
  const float* C_b    = (const float*)d_in[9];
  const float* out_w  = (const float*)d_in[10];
  const float* out_b  = (const float*)d_in[11];
  const float* ln_w   = (const float*)d_in[12];
  const float* ln_b   = (const float*)d_in[13];
  float* out = (float*)d_out;

  // workspace layout (~138.3 MB). xb region is reused for y; xz region for h.
  char* ws = (char*)d_ws;
  bf16* xb_y    = (bf16*)(ws + 0);            // 33,554,432 B : x as bf16, later y
  bf16* xz      = (bf16*)(ws + 33554432);     // 67,108,864 B : xz bf16 [M][2D]
  float* h      = (float*)(ws + 33554432);    // reuse: h fp32 [M][D] (same size)
  bf16* xc      = (bf16*)(ws + 100663296);    // 33,554,432 B : conv+silu out bf16
  float* BC     = (float*)(ws + 134217728);   //  4,194,304 B : Bm|Cm fp32 [M][64]
  bf16* in_wb   = (bf16*)(ws + 138412032);    //  4,194,304 B
  bf16* out_wb  = (bf16*)(ws + 142606336);    //  2,097,152 B
  bf16* bcw     = (bf16*)(ws + 144703488);    //    131,072 B : [64][1024]
  float* Aexp   = (float*)(ws + 144834560);   //    131,072 B : [D][N]
  float* bias_bc= (float*)(ws + 144965632);   //        256 B

  cvt_x_kernel<<<(B_ * L_ * D_ / 4) / 256, 256, 0, stream>>>(x, xb_y);
  cvt_w_kernel<<<1024, 256, 0, stream>>>(in_w, out_w, B_w, C_w, A_log, B_b, C_b,
                                         in_wb, out_wb, bcw, Aexp, bias_bc);
  // xz[M,2D] = xb @ in_w^T + in_b (bf16 out)
  gemm_kernel<128, 128, 2, 2, true, false>
      <<<dim3(MTOT / 128, (2 * D_) / 128), 256, 0, stream>>>(
          xb_y, in_wb, in_b, nullptr, xz, 2 * D_, D_);
  conv_silu_kernel<<<(B_ * L_ * D_ / 8) / 256, 256, 0, stream>>>(xz, conv_w, conv_b, xc);
  // BC[M,64] = xc @ [B_w;C_w]^T + [B_b;C_b] (fp32 out)
  gemm_kernel<128, 64, 2, 2, false, false>
      <<<dim3(MTOT / 128, 1), 256, 0, stream>>>(xc, bcw, bias_bc, nullptr, BC, 64, D_);
  // y[M,D] = gated scan output (bf16), overwrites xb region
  scan_kernel<<<dim3(D_ / 256, L_ / TCH, B_), 256, 0, stream>>>(xc, BC, xz, Aexp, xb_y);
  // h[M,D] = y @ out_w^T + out_b + x (fp32), overwrites xz region
  gemm_kernel<128, 128, 2, 2, false, true>
      <<<dim3(MTOT / 128, D_ / 128), 256, 0, stream>>>(
          xb_y, out_wb, out_b, x, h, D_, D_);
  ln_kernel<<<MTOT, 256, 0, stream>>>(h, ln_w, ln_b, out);
}

// Round 2
// 388.260 us; speedup vs baseline: 1.1901x; 1.1901x over previous
//
#include <hip/hip_runtime.h>
#include <hip/hip_bf16.h>

#define B_ 4
#define L_ 4096
#define D_ 1024
#define N_ 32
#define MTOT (B_*L_)   // 16384
#define TCH 32         // scan chunk length
#define WARM 16        // scan warm-up steps (|A|^16 ~ 6e-11)
#define STEPS (TCH + WARM)

typedef __bf16 bf16;
typedef __attribute__((ext_vector_type(8))) __bf16 bf16x8;
typedef __attribute__((ext_vector_type(4))) __bf16 bf16x4;
typedef __attribute__((ext_vector_type(4))) float f32x4;

__device__ __forceinline__ void gload_lds16(const void* gsrc, void* ldst) {
  // global -> LDS direct, 16B per lane. LDS dest is wave-uniform base + lane*16.
  __builtin_amdgcn_global_load_lds(
      (__attribute__((address_space(1))) void*)(unsigned long long)gsrc,
      (__attribute__((address_space(3))) void*)ldst, 16, 0, 0);
}

// ---------------- convert x -> bf16 ----------------
__global__ __launch_bounds__(256) void cvt_x_kernel(const float* __restrict__ x,
                                                    bf16* __restrict__ xb) {
  size_t i = ((size_t)blockIdx.x * 256 + threadIdx.x) * 4;
  float4 v = *(const float4*)(x + i);
  bf16x4 o = {(bf16)v.x, (bf16)v.y, (bf16)v.z, (bf16)v.w};
  *(bf16x4*)(xb + i) = o;
}

// ---------------- convert weights, build A = -exp(clip(A_log)) ----------------
__global__ __launch_bounds__(256) void cvt_w_kernel(
    const float* __restrict__ in_w, const float* __restrict__ out_w,
    const float* __restrict__ B_w, const float* __restrict__ C_w,
    const float* __restrict__ A_log, const float* __restrict__ B_b,
    const float* __restrict__ C_b,
    bf16* __restrict__ in_wb, bf16* __restrict__ out_wb, bf16* __restrict__ bcw,
    float* __restrict__ Aexp, float* __restrict__ bias_bc) {
  const int stride = gridDim.x * 256;
  const int i0 = blockIdx.x * 256 + threadIdx.x;
  for (int j = i0; j < 2 * D_ * D_; j += stride) in_wb[j] = (bf16)in_w[j];
  for (int j = i0; j < D_ * D_; j += stride) out_wb[j] = (bf16)out_w[j];
  for (int j = i0; j < N_ * D_; j += stride) {
    bcw[j] = (bf16)B_w[j];
    bcw[N_ * D_ + j] = (bf16)C_w[j];
  }
  for (int j = i0; j < D_ * N_; j += stride)
    Aexp[j] = -expf(fminf(fmaxf(A_log[j], -5.f), 2.f));
  if (i0 < N_) { bias_bc[i0] = B_b[i0]; bias_bc[N_ + i0] = C_b[i0]; }
}

// ---------------- generic bf16 MFMA GEMM: C[M,Ncols] = A[M,K] @ W[Ncols,K]^T + bias (+resid) ----
template <int BM, int BN, int WAVES_M, int WAVES_N, bool OUT_BF16, bool ADD_RESID>
__global__ __launch_bounds__(256) void gemm_kernel(
    const bf16* __restrict__ Ag, const bf16* __restrict__ Wg,
    const float* __restrict__ bias, const float* __restrict__ resid,
    void* __restrict__ Cg, int Ncols, int K) {
  constexpr int BK = 32;
  constexpr int WM = BM / WAVES_M;
  constexpr int WN = BN / WAVES_N;
  constexpr int MI = WM / 16;
  constexpr int NI = WN / 16;
  __shared__ alignas(16) bf16 As[BM][BK];
  __shared__ alignas(16) bf16 Bs[BN][BK];
  const int tid = threadIdx.x;
  const int lane = tid & 63;
  const int wid = tid >> 6;
  const int wm = wid / WAVES_N;
  const int wn = wid % WAVES_N;
  const int l15 = lane & 15;
  const int lh = lane >> 4;
  const int row0 = blockIdx.x * BM;
  const int col0 = blockIdx.y * BN;

  f32x4 acc[MI][NI] = {};

  for (int k0 = 0; k0 < K; k0 += BK) {
    // stage A tile [BM][BK] (rows of 64B, linear LDS)
#pragma unroll
    for (int i = 0; i < (BM * BK * 2 / 16) / 256; ++i) {
      const int chunk = tid + i * 256;
      const int o = chunk * 16;
      const int r = o >> 6;
      const int kb = (o & 63) >> 1;
      gload_lds16(Ag + (size_t)(row0 + r) * K + (k0 + kb),
                  (bf16*)&As[0][0] + (size_t)(wid * 64 + i * 256) * 8);
    }
    // stage W tile [BN][BK]
#pragma unroll
    for (int i = 0; i < (BN * BK * 2 / 16) / 256; ++i) {
      const int chunk = tid + i * 256;
      const int o = chunk * 16;
      const int r = o >> 6;
      const int kb = (o & 63) >> 1;
      gload_lds16(Wg + (size_t)(col0 + r) * K + (k0 + kb),
                  (bf16*)&Bs[0][0] + (size_t)(wid * 64 + i * 256) * 8);
    }
    __syncthreads();  // drains vmcnt (incl. global_load_lds) before reads

    bf16x8 af[MI], bfv[NI];
#pragma unroll
    for (int mi = 0; mi < MI; ++mi)
      af[mi] = *(const bf16x8*)&As[wm * WM + mi * 16 + l15][lh * 8];
#pragma unroll
    for (int ni = 0; ni < NI; ++ni)
      bfv[ni] = *(const bf16x8*)&Bs[wn * WN + ni * 16 + l15][lh * 8];
#pragma unroll
    for (int mi = 0; mi < MI; ++mi)
#pragma unroll
      for (int ni = 0; ni < NI; ++ni)
        acc[mi][ni] = __builtin_amdgcn_mfma_f32_16x16x32_bf16(
            af[mi], bfv[ni], acc[mi][ni], 0, 0, 0);
    __syncthreads();  // protect LDS before next-iter overwrite
  }

  // epilogue: C/D layout col=lane&15, row=(lane>>4)*4+reg
#pragma unroll
  for (int mi = 0; mi < MI; ++mi) {
#pragma unroll
    for (int ni = 0; ni < NI; ++ni) {
      const int c = col0 + wn * WN + ni * 16 + l15;
      const float bv = bias[c];
#pragma unroll
      for (int j = 0; j < 4; ++j) {
        const int r = row0 + wm * WM + mi * 16 + lh * 4 + j;
        float v = acc[mi][ni][j] + bv;
        if constexpr (ADD_RESID) v += resid[(size_t)r * Ncols + c];
        if constexpr (OUT_BF16)
          ((bf16*)Cg)[(size_t)r * Ncols + c] = (bf16)v;
        else
          ((float*)Cg)[(size_t)r * Ncols + c] = v;
      }
    }
  }
}

// ---------------- depthwise conv(k=4, pad 2) + bias + SiLU ----------------
__global__ __launch_bounds__(256) void conv_silu_kernel(
    const bf16* __restrict__ xz, const float* __restrict__ conv_w,
    const float* __restrict__ conv_b, bf16* __restrict__ xc) {
  const int idx = blockIdx.x * 256 + threadIdx.x;  // B*L*(D/8) threads
  const int d8 = idx & (D_ / 8 - 1);
  const int bt = idx >> 7;          // D_/8 == 128
  const int t = bt & (L_ - 1);
  const int b = bt >> 12;           // L_ == 4096
  const int d = d8 * 8;

  float accv[8];
  float4 w4[8];
#pragma unroll
  for (int j = 0; j < 8; ++j) {
    accv[j] = conv_b[d + j];
    w4[j] = *(const float4*)(conv_w + (size_t)(d + j) * 4);
  }
#pragma unroll
  for (int k = 0; k < 4; ++k) {
    const int tt = t + k - 2;
    if (tt < 0 || tt >= L_) continue;
    const bf16x8 xv = *(const bf16x8*)(xz + (size_t)(b * L_ + tt) * (2 * D_) + d);
#pragma unroll
    for (int j = 0; j < 8; ++j) {
      const float wk = (k == 0) ? w4[j].x : (k == 1) ? w4[j].y : (k == 2) ? w4[j].z : w4[j].w;
      accv[j] += (float)xv[j] * wk;
    }
  }
  bf16x8 o;
#pragma unroll
  for (int j = 0; j < 8; ++j) {
    const float v = accv[j];
    o[j] = (bf16)(v / (1.f + __expf(-v)));
  }
  *(bf16x8*)(xc + (size_t)(b * L_ + t) * D_ + d) = o;
}

// ---------------- chunked selective scan + SiLU(z) gating ----------------
// One block = 256 d-channels x one 32-step chunk of one batch. 16-step warm-up.
// B/C rows for the chunk staged in LDS once (12 KB), read as uniform broadcasts.
__global__ __launch_bounds__(256) void scan_kernel(
    const bf16* __restrict__ xc, const float* __restrict__ BC,
    const bf16* __restrict__ xz, const float* __restrict__ Aexp,
    bf16* __restrict__ y) {
  const int dg = blockIdx.x, chunk = blockIdx.y, b = blockIdx.z;
  const int tid = threadIdx.x;
  const int wid = tid >> 6;
  const int d = dg * 256 + tid;
  const int t0 = chunk * TCH;
  const int tstart = (t0 >= WARM) ? (t0 - WARM) : 0;
  const int tend = t0 + TCH;

  __shared__ float bcs[STEPS][64];  // 12 KB
#pragma unroll
  for (int i = 0; i < (STEPS * 64 * 4 / 16) / 256; ++i) {
    gload_lds16(BC + ((size_t)b * L_ + tstart) * 64 + (size_t)(tid + i * 256) * 4,
                (float*)&bcs[0][0] + (size_t)(wid * 64 + i * 256) * 4);
  }

  float Ar[N_], s[N_];
#pragma unroll
  for (int n = 0; n < N_; ++n) { Ar[n] = Aexp[d * N_ + n]; s[n] = 0.f; }

  const bf16* xcp = xc + (size_t)b * L_ * D_ + d;
  const bf16* zp  = xz + (size_t)b * L_ * (2 * D_) + D_ + d;
  bf16* yp        = y + (size_t)b * L_ * D_ + d;

  __syncthreads();  // staged BC ready

#pragma unroll 4
  for (int i = 0; i < STEPS; ++i) {
    const int t = tstart + i;
    const float4* rp = (const float4*)&bcs[i][0];  // uniform -> LDS broadcast
    const float xt = (float)xcp[(size_t)t * D_];
    float y0 = 0.f, y1 = 0.f, y2 = 0.f, y3 = 0.f;
#pragma unroll
    for (int q = 0; q < 8; ++q) {
      const float4 bv = rp[q];
      const float4 cv = rp[8 + q];
      { const int n = 4*q;   s[n] = fminf(fmaxf(fmaf(s[n], Ar[n], bv.x * xt), -10.f), 10.f); y0 = fmaf(cv.x, s[n], y0); }
      { const int n = 4*q+1; s[n] = fminf(fmaxf(fmaf(s[n], Ar[n], bv.y * xt), -10.f), 10.f); y1 = fmaf(cv.y, s[n], y1); }
      { const int n = 4*q+2; s[n] = fminf(fmaxf(fmaf(s[n], Ar[n], bv.z * xt), -10.f), 10.f); y2 = fmaf(cv.z, s[n], y2); }
      { const int n = 4*q+3; s[n] = fminf(fmaxf(fmaf(s[n], Ar[n], bv.w * xt), -10.f), 10.f); y3 = fmaf(cv.w, s[n], y3); }
    }
    if (t >= t0 && t < tend) {
      const float zt = (float)zp[(size_t)t * (2 * D_)];
      const float sz = zt / (1.f + __expf(-zt));
      yp[(size_t)t * D_] = (bf16)(((y0 + y1) + (y2 + y3)) * sz);
    }
  }
}

// ---------------- row LayerNorm ----------------
__global__ __launch_bounds__(256) void ln_kernel(const float* __restrict__ h,
                                                 const float* __restrict__ ln_w,
                                                 const float* __restrict__ ln_b,
                                                 float* __restrict__ out) {
  const int row = blockIdx.x;
  const int tid = threadIdx.x;
  const float4 v = ((const float4*)(h + (size_t)row * D_))[tid];
  float sum = v.x + v.y + v.z + v.w;
  float sq = v.x * v.x + v.y * v.y + v.z * v.z + v.w * v.w;
#pragma unroll
  for (int off = 32; off >= 1; off >>= 1) {
    sum += __shfl_xor(sum, off);
    sq += __shfl_xor(sq, off);
  }
  __shared__ float red[8];
  const int wid = tid >> 6;
  if ((tid & 63) == 0) { red[wid] = sum; red[4 + wid] = sq; }
  __syncthreads();
  sum = red[0] + red[1] + red[2] + red[3];
  sq = red[4] + red[5] + red[6] + red[7];
  const float mu = sum * (1.f / D_);
  const float var = sq * (1.f / D_) - mu * mu;
  const float inv = rsqrtf(var + 1e-5f);
  const float4 w4 = ((const float4*)ln_w)[tid];
  const float4 b4 = ((const float4*)ln_b)[tid];
  float4 o;
  o.x = (v.x - mu) * inv * w4.x + b4.x;
  o.y = (v.y - mu) * inv * w4.y + b4.y;
  o.z = (v.z - mu) * inv * w4.z + b4.z;
  o.w = (v.w - mu) * inv * w4.w + b4.w;
  ((float4*)(out + (size_t)row * D_))[tid] = o;
}

extern "C" void kernel_launch(void* const* d_in, const int* in_sizes, int n_in,
                              void* d_out, int out_size, void* d_ws, size_t ws_size,
                              hipStream_t stream) {
  (void)in_sizes; (void)n_in; (void)out_size; (void)ws_size;
  const float* x      = (const float*)d_in[0];
  const float* in_w   = (const float*)d_in[1];
  const float* in_b   = (const float*)d_in[2];
  const float* conv_w = (const float*)d_in[3];
  const float* conv_b = (const float*)d_in[4];
  const float* A_log  = (const float*)d_in[5];
  const float* B_w    = (const float*)d_in[6];
  const float* B_b    = (const float*)d_in[7];
  const float* C_w    = (const float*)d_in[8];
  const float* C_b    = (const float*)d_in[9];
  const float* out_w  = (const float*)d_in[10];
  const float* out_b  = (const float*)d_in[11];
  const float* ln_w   = (const float*)d_in[12];
  const float* ln_b   = (const float*)d_in[13];
  float* out = (float*)d_out;

  // workspace layout (~138.3 MB). xb region is reused for y; xz region for h.
  char* ws = (char*)d_ws;
  bf16* xb_y    = (bf16*)(ws + 0);            // 33,554,432 B : x as bf16, later y
  bf16* xz      = (bf16*)(ws + 33554432);     // 67,108,864 B : xz bf16 [M][2D]
  float* h      = (float*)(ws + 33554432);    // reuse: h fp32 [M][D] (same size)
  bf16* xc      = (bf16*)(ws + 100663296);    // 33,554,432 B : conv+silu out bf16
  float* BC     = (float*)(ws + 134217728);   //  4,194,304 B : Bm|Cm fp32 [M][64]
  bf16* in_wb   = (bf16*)(ws + 138412032);    //  4,194,304 B
  bf16* out_wb  = (bf16*)(ws + 142606336);    //  2,097,152 B
  bf16* bcw     = (bf16*)(ws + 144703488);    //    131,072 B : [64][1024]
  float* Aexp   = (float*)(ws + 144834560);   //    131,072 B : [D][N]
  float* bias_bc= (float*)(ws + 144965632);   //        256 B

  cvt_x_kernel<<<(B_ * L_ * D_ / 4) / 256, 256, 0, stream>>>(x, xb_y);
  cvt_w_kernel<<<1024, 256, 0, stream>>>(in_w, out_w, B_w, C_w, A_log, B_b, C_b,
                                         in_wb, out_wb, bcw, Aexp, bias_bc);
  // xz[M,2D] = xb @ in_w^T + in_b (bf16 out)
  gemm_kernel<128, 128, 2, 2, true, false>
      <<<dim3(MTOT / 128, (2 * D_) / 128), 256, 0, stream>>>(
          xb_y, in_wb, in_b, nullptr, xz, 2 * D_, D_);
  conv_silu_kernel<<<(B_ * L_ * D_ / 8) / 256, 256, 0, stream>>>(xz, conv_w, conv_b, xc);
  // BC[M,64] = xc @ [B_w;C_w]^T + [B_b;C_b] (fp32 out); 64x64 tile -> 256 blocks
  gemm_kernel<64, 64, 2, 2, false, false>
      <<<dim3(MTOT / 64, 1), 256, 0, stream>>>(xc, bcw, bias_bc, nullptr, BC, 64, D_);
  // y[M,D] = gated scan output (bf16), overwrites xb region
  scan_kernel<<<dim3(D_ / 256, L_ / TCH, B_), 256, 0, stream>>>(xc, BC, xz, Aexp, xb_y);
  // h[M,D] = y @ out_w^T + out_b + x (fp32), overwrites xz region
  gemm_kernel<128, 128, 2, 2, false, true>
      <<<dim3(MTOT / 128, D_ / 128), 256, 0, stream>>>(
          xb_y, out_wb, out_b, x, h, D_, D_);
  ln_kernel<<<MTOT, 256, 0, stream>>>(h, ln_w, ln_b, out);
}